// Round 1
// baseline (1609.027 us; speedup 1.0000x reference)
//
#include <hip/hip_runtime.h>
#include <hip/hip_bf16.h>
#include <math.h>

// Problem constants
#define NC 3
#define NK 64
#define KK 3
#define K2 9
#define PAD 1
#define SCALE 4
#define S2 16
#define MID 4
#define B 4
#define H 128
#define W 128
#define HW (H*W)          // 16384
#define CIN 67            // NK + NC
#define OUT_HW (H*SCALE)  // 512

__device__ __forceinline__ float sigmoidf_(float v) { return 1.f / (1.f + expf(-v)); }

// load a zero-padded 3x3 patch of one channel plane (HxW) at (y,x)
__device__ __forceinline__ void load_patch(const float* __restrict__ xc, int y, int x, float* p) {
#pragma unroll
    for (int dy = -1; dy <= 1; dy++) {
#pragma unroll
        for (int dx = -1; dx <= 1; dx++) {
            int yy = y + dy, xx = x + dx;
            float v = (yy >= 0 && yy < H && xx >= 0 && xx < W) ? xc[yy * W + xx] : 0.f;
            p[(dy + 1) * 3 + (dx + 1)] = v;
        }
    }
}

// ---------------------------------------------------------------------------
// ConvLSTM with h=0,c=0: only first NC input channels of lstm_w matter;
// f-gate irrelevant (c_prev=0). Writes hid->(d_out hid section, xcatA ch0..63),
// cell->d_out, and copies X into xcatA ch64..66.
// ---------------------------------------------------------------------------
__global__ __launch_bounds__(256) void k_lstm(const float* __restrict__ X,
                                              const float* __restrict__ lw,
                                              const float* __restrict__ lb,
                                              float* __restrict__ xcatA,
                                              float* __restrict__ hid_out,
                                              float* __restrict__ cell_out) {
    int t = blockIdx.x * blockDim.x + threadIdx.x;
    int b = t >> 14, hw = t & (HW - 1), y = hw >> 7, x = hw & (W - 1);
    float p[NC][9];
#pragma unroll
    for (int c = 0; c < NC; c++) load_patch(X + (b * NC + c) * HW, y, x, p[c]);
    float* xc = xcatA + (size_t)b * CIN * HW;
    for (int nk = 0; nk < NK; nk++) {
        float gi = lb[nk], go = lb[2 * NK + nk], gg = lb[3 * NK + nk];
#pragma unroll
        for (int c = 0; c < NC; c++) {
            const float* wi = lw + (size_t)(nk) * (CIN * 9) + c * 9;
            const float* wo = lw + (size_t)(2 * NK + nk) * (CIN * 9) + c * 9;
            const float* wg = lw + (size_t)(3 * NK + nk) * (CIN * 9) + c * 9;
#pragma unroll
            for (int tt = 0; tt < 9; tt++) {
                gi += p[c][tt] * wi[tt];
                go += p[c][tt] * wo[tt];
                gg += p[c][tt] * wg[tt];
            }
        }
        float cv = sigmoidf_(gi) * tanhf(gg);
        float hv = sigmoidf_(go) * tanhf(cv);
        xc[nk * HW + hw] = hv;
        hid_out[(b * NK + nk) * HW + hw] = hv;
        cell_out[(b * NK + nk) * HW + hw] = cv;
    }
#pragma unroll
    for (int c = 0; c < NC; c++) xc[(NK + c) * HW + hw] = X[(b * NC + c) * HW + hw];
}

// copy lr (X) into channels 64..66 of an xcat buffer
__global__ __launch_bounds__(256) void k_copy_lr(const float* __restrict__ X,
                                                 float* __restrict__ xcat) {
    int t = blockIdx.x * blockDim.x + threadIdx.x;
    int b = t >> 14, hw = t & (HW - 1);
    float* xc = xcat + (size_t)b * CIN * HW;
#pragma unroll
    for (int c = 0; c < NC; c++) xc[(NK + c) * HW + hw] = X[(b * NC + c) * HW + hw];
}

// transpose deform main weight [64][603] -> [603][64] for float4 inner loops
__global__ void k_transw(const float* __restrict__ w, float* __restrict__ wT) {
    int i = blockIdx.x * blockDim.x + threadIdx.x;
    if (i < NK * CIN * K2) {
        int o = i / (CIN * K2), ck = i % (CIN * K2);
        wT[ck * NK + o] = w[i];
    }
}

// ---------------------------------------------------------------------------
// Offset + mask convs for one deform layer. 27 accumulators per thread.
// Stores offsets raw, mask as 2*sigmoid.
// ---------------------------------------------------------------------------
__global__ __launch_bounds__(256) void k_offmask(const float* __restrict__ xcat,
                                                 const float* __restrict__ ow,
                                                 const float* __restrict__ ob,
                                                 const float* __restrict__ mw,
                                                 const float* __restrict__ mb,
                                                 float* __restrict__ offb,
                                                 float* __restrict__ maskb) {
    int t = blockIdx.x * blockDim.x + threadIdx.x;
    int b = t >> 14, hw = t & (HW - 1), y = hw >> 7, x = hw & (W - 1);
    float acc[27];
#pragma unroll
    for (int i = 0; i < 18; i++) acc[i] = ob[i];
#pragma unroll
    for (int i = 0; i < 9; i++) acc[18 + i] = mb[i];
    const float* xb = xcat + (size_t)b * CIN * HW;
    for (int c = 0; c < CIN; c++) {
        float p[9];
        load_patch(xb + c * HW, y, x, p);
#pragma unroll
        for (int oc = 0; oc < 18; oc++) {
            const float* w = ow + (size_t)oc * (CIN * 9) + c * 9;
#pragma unroll
            for (int tt = 0; tt < 9; tt++) acc[oc] += p[tt] * w[tt];
        }
#pragma unroll
        for (int oc = 0; oc < 9; oc++) {
            const float* w = mw + (size_t)oc * (CIN * 9) + c * 9;
#pragma unroll
            for (int tt = 0; tt < 9; tt++) acc[18 + oc] += p[tt] * w[tt];
        }
    }
#pragma unroll
    for (int oc = 0; oc < 18; oc++) offb[(b * 18 + oc) * HW + hw] = acc[oc];
#pragma unroll
    for (int oc = 0; oc < 9; oc++) maskb[(b * 9 + oc) * HW + hw] = 2.f * sigmoidf_(acc[18 + oc]);
}

// ---------------------------------------------------------------------------
// Deformable gather + einsum. Per thread: 9 taps, for each tap the 4 bilinear
// corner weights (mask folded in) and clamped indices; per channel gather one
// value then 64 FMAs against wT (contiguous float4, wave-uniform -> broadcast).
// Writes 64 channels into the destination xcat buffer (lr channels untouched).
// ---------------------------------------------------------------------------
__global__ __launch_bounds__(256) void k_deform(const float* __restrict__ xcat,
                                                const float* __restrict__ offb,
                                                const float* __restrict__ maskb,
                                                const float* __restrict__ wT,
                                                const float* __restrict__ bias,
                                                float* __restrict__ xout) {
    int t = blockIdx.x * blockDim.x + threadIdx.x;
    int b = t >> 14, hw = t & (HW - 1), y = hw >> 7, x = hw & (W - 1);
    float acc[NK];
#pragma unroll
    for (int o = 0; o < NK; o++) acc[o] = 0.f;
    const float* xb = xcat + (size_t)b * CIN * HW;
    for (int k = 0; k < K2; k++) {
        int ky = k / 3, kx = k % 3;
        float offy = offb[(b * 18 + 2 * k) * HW + hw];
        float offx = offb[(b * 18 + 2 * k + 1) * HW + hw];
        float m = maskb[(b * 9 + k) * HW + hw];
        float py = (float)(y + ky - 1) + offy;
        float px = (float)(x + kx - 1) + offx;
        float fy = floorf(py), fx = floorf(px);
        float wy = py - fy, wx = px - fx;
        int y0 = (int)fy, x0 = (int)fx;
        int y1 = y0 + 1, x1 = x0 + 1;
        float vy0 = (y0 >= 0 && y0 <= H - 1) ? 1.f : 0.f;
        float vy1 = (y1 >= 0 && y1 <= H - 1) ? 1.f : 0.f;
        float vx0 = (x0 >= 0 && x0 <= W - 1) ? 1.f : 0.f;
        float vx1 = (x1 >= 0 && x1 <= W - 1) ? 1.f : 0.f;
        int yc0 = min(max(y0, 0), H - 1), yc1 = min(max(y1, 0), H - 1);
        int xc0 = min(max(x0, 0), W - 1), xc1 = min(max(x1, 0), W - 1);
        float w00 = (1.f - wy) * (1.f - wx) * m * vy0 * vx0;
        float w01 = (1.f - wy) * wx * m * vy0 * vx1;
        float w10 = wy * (1.f - wx) * m * vy1 * vx0;
        float w11 = wy * wx * m * vy1 * vx1;
        int i00 = yc0 * W + xc0, i01 = yc0 * W + xc1;
        int i10 = yc1 * W + xc0, i11 = yc1 * W + xc1;
        for (int c = 0; c < CIN; c++) {
            const float* xc = xb + c * HW;
            float v = w00 * xc[i00] + w01 * xc[i01] + w10 * xc[i10] + w11 * xc[i11];
            const float4* wv = (const float4*)(wT + ((size_t)c * K2 + k) * NK);
#pragma unroll
            for (int o4 = 0; o4 < NK / 4; o4++) {
                float4 wq = wv[o4];
                acc[o4 * 4 + 0] += v * wq.x;
                acc[o4 * 4 + 1] += v * wq.y;
                acc[o4 * 4 + 2] += v * wq.z;
                acc[o4 * 4 + 3] += v * wq.w;
            }
        }
    }
    float* xo = xout + (size_t)b * CIN * HW;
#pragma unroll
    for (int o = 0; o < NK; o++) xo[o * HW + hw] = acc[o] + bias[o];
}

// final 3-channel conv over 67-channel concat
__global__ __launch_bounds__(256) void k_conv3(const float* __restrict__ xcat,
                                               const float* __restrict__ cw,
                                               const float* __restrict__ cb,
                                               float* __restrict__ y3) {
    int t = blockIdx.x * blockDim.x + threadIdx.x;
    int b = t >> 14, hw = t & (HW - 1), y = hw >> 7, x = hw & (W - 1);
    float acc[NC] = {cb[0], cb[1], cb[2]};
    const float* xb = xcat + (size_t)b * CIN * HW;
    for (int c = 0; c < CIN; c++) {
        float p[9];
        load_patch(xb + c * HW, y, x, p);
#pragma unroll
        for (int oc = 0; oc < NC; oc++) {
            const float* w = cw + (size_t)oc * (CIN * 9) + c * 9;
#pragma unroll
            for (int tt = 0; tt < 9; tt++) acc[oc] += p[tt] * w[tt];
        }
    }
#pragma unroll
    for (int oc = 0; oc < NC; oc++) y3[(b * NC + oc) * HW + hw] = acc[oc];
}

// global average pool: one block per (b,c)
__global__ __launch_bounds__(256) void k_pool(const float* __restrict__ y3,
                                              float* __restrict__ pooled) {
    int bc = blockIdx.x;  // 0..11
    const float* p = y3 + (size_t)bc * HW;
    float s = 0.f;
    for (int i = threadIdx.x; i < HW; i += 256) s += p[i];
    __shared__ float red[256];
    red[threadIdx.x] = s;
    __syncthreads();
    for (int off = 128; off > 0; off >>= 1) {
        if (threadIdx.x < off) red[threadIdx.x] += red[threadIdx.x + off];
        __syncthreads();
    }
    if (threadIdx.x == 0) pooled[bc] = red[0] / (float)HW;
}

// tiny per-branch channel MLP -> ch[b,s,c,k]
__global__ void k_ch(const float* __restrict__ pooled, const float* __restrict__ w1,
                     const float* __restrict__ b1, const float* __restrict__ w2,
                     const float* __restrict__ b2, float* __restrict__ chbuf) {
    int t = threadIdx.x;
    if (t >= B * S2) return;
    int b = t >> 4, s = t & 15;
    float h1[MID];
#pragma unroll
    for (int m = 0; m < MID; m++) {
        float a = b1[s * MID + m];
#pragma unroll
        for (int c = 0; c < NC; c++) a += pooled[b * NC + c] * w1[(s * MID + m) * NC + c];
        h1[m] = fmaxf(a, 0.f);
    }
    for (int kk = 0; kk < NC * K2; kk++) {
        float a = b2[s * (NC * K2) + kk];
#pragma unroll
        for (int m = 0; m < MID; m++) a += h1[m] * w2[(s * (NC * K2) + kk) * MID + m];
        chbuf[(b * S2 + s) * (NC * K2) + kk] = a;
    }
}

// ---------------------------------------------------------------------------
// Fused DDF upsample: spatial-filter conv + dynamic combine + pixel_shuffle
// + clip. sp_w / sp_b / ch staged in LDS (block is single-batch).
// ---------------------------------------------------------------------------
__global__ __launch_bounds__(256) void k_ddf(const float* __restrict__ y3,
                                             const float* __restrict__ spw,
                                             const float* __restrict__ spb,
                                             const float* __restrict__ chbuf,
                                             float* __restrict__ out) {
    __shared__ float s_spw[S2 * K2 * NC * 9];  // 3888
    __shared__ float s_spb[S2 * K2];           // 144
    __shared__ float s_ch[S2 * NC * K2];       // 432
    int t = blockIdx.x * blockDim.x + threadIdx.x;
    int b = t >> 14, hw = t & (HW - 1), y = hw >> 7, x = hw & (W - 1);
    for (int i = threadIdx.x; i < S2 * K2 * NC * 9; i += 256) s_spw[i] = spw[i];
    for (int i = threadIdx.x; i < S2 * K2; i += 256) s_spb[i] = spb[i];
    for (int i = threadIdx.x; i < S2 * NC * K2; i += 256) s_ch[i] = chbuf[b * (S2 * NC * K2) + i];
    __syncthreads();
    float p[NC][9];
#pragma unroll
    for (int c = 0; c < NC; c++) load_patch(y3 + (b * NC + c) * HW, y, x, p[c]);
    for (int s = 0; s < S2; s++) {
        float spv[K2];
#pragma unroll
        for (int k = 0; k < K2; k++) {
            float a = s_spb[s * K2 + k];
            const float* w = s_spw + (s * K2 + k) * (NC * 9);
#pragma unroll
            for (int c = 0; c < NC; c++)
#pragma unroll
                for (int tt = 0; tt < 9; tt++) a += p[c][tt] * w[c * 9 + tt];
            spv[k] = a;
        }
        int sy = s >> 2, sx = s & 3;
#pragma unroll
        for (int c = 0; c < NC; c++) {
            float a = 0.f;
            const float* chp = s_ch + (s * NC + c) * K2;
#pragma unroll
            for (int k = 0; k < K2; k++) a += p[c][k] * (chp[k] + spv[k]);
            a = fminf(fmaxf(a, 0.f), 255.f);
            out[((size_t)(b * NC + c) * OUT_HW + (y * SCALE + sy)) * OUT_HW + (x * SCALE + sx)] = a;
        }
    }
}

extern "C" void kernel_launch(void* const* d_in, const int* in_sizes, int n_in,
                              void* d_out, int out_size, void* d_ws, size_t ws_size,
                              hipStream_t stream) {
    const float* X = (const float*)d_in[0];
    const float* lstm_w = (const float*)d_in[1];
    const float* lstm_b = (const float*)d_in[2];
    const float* ow[3] = {(const float*)d_in[3], (const float*)d_in[9], (const float*)d_in[15]};
    const float* ob[3] = {(const float*)d_in[4], (const float*)d_in[10], (const float*)d_in[16]};
    const float* mw[3] = {(const float*)d_in[5], (const float*)d_in[11], (const float*)d_in[17]};
    const float* mb[3] = {(const float*)d_in[6], (const float*)d_in[12], (const float*)d_in[18]};
    const float* dw[3] = {(const float*)d_in[7], (const float*)d_in[13], (const float*)d_in[19]};
    const float* db[3] = {(const float*)d_in[8], (const float*)d_in[14], (const float*)d_in[20]};
    const float* conv_w = (const float*)d_in[21];
    const float* conv_b = (const float*)d_in[22];
    const float* sp_w = (const float*)d_in[23];
    const float* sp_b = (const float*)d_in[24];
    const float* ch_w1 = (const float*)d_in[25];
    const float* ch_b1 = (const float*)d_in[26];
    const float* ch_w2 = (const float*)d_in[27];
    const float* ch_b2 = (const float*)d_in[28];

    float* out = (float*)d_out;
    const size_t OUT_IMG = (size_t)B * NC * OUT_HW * OUT_HW;  // 3145728
    const size_t HIDSZ = (size_t)B * NK * HW;                 // 4194304
    float* hid_out = out + OUT_IMG;
    float* cell_out = out + OUT_IMG + HIDSZ;

    float* ws = (float*)d_ws;
    const size_t XCAT = (size_t)B * CIN * HW;  // 4390912
    float* xcatA = ws;            ws += XCAT;
    float* xcatB = ws;            ws += XCAT;
    float* offb = ws;             ws += (size_t)B * 18 * HW;
    float* maskb = ws;            ws += (size_t)B * 9 * HW;
    float* wT[3];
    for (int i = 0; i < 3; i++) { wT[i] = ws; ws += NK * CIN * K2; }
    float* y3 = ws;               ws += (size_t)B * NC * HW;
    float* pooled = ws;           ws += 16;
    float* chbuf = ws;            ws += (size_t)B * S2 * NC * K2;

    dim3 blk(256);
    dim3 grd(B * HW / 256);  // 256 blocks

    k_lstm<<<grd, blk, 0, stream>>>(X, lstm_w, lstm_b, xcatA, hid_out, cell_out);
    k_copy_lr<<<grd, blk, 0, stream>>>(X, xcatB);
    int ntw = NK * CIN * K2;
    for (int i = 0; i < 3; i++)
        k_transw<<<(ntw + 255) / 256, 256, 0, stream>>>(dw[i], wT[i]);

    // layer 1: xcatA -> xcatB
    k_offmask<<<grd, blk, 0, stream>>>(xcatA, ow[0], ob[0], mw[0], mb[0], offb, maskb);
    k_deform<<<grd, blk, 0, stream>>>(xcatA, offb, maskb, wT[0], db[0], xcatB);
    // layer 2: xcatB -> xcatA
    k_offmask<<<grd, blk, 0, stream>>>(xcatB, ow[1], ob[1], mw[1], mb[1], offb, maskb);
    k_deform<<<grd, blk, 0, stream>>>(xcatB, offb, maskb, wT[1], db[1], xcatA);
    // layer 3: xcatA -> xcatB
    k_offmask<<<grd, blk, 0, stream>>>(xcatA, ow[2], ob[2], mw[2], mb[2], offb, maskb);
    k_deform<<<grd, blk, 0, stream>>>(xcatA, offb, maskb, wT[2], db[2], xcatB);

    k_conv3<<<grd, blk, 0, stream>>>(xcatB, conv_w, conv_b, y3);
    k_pool<<<dim3(B * NC), blk, 0, stream>>>(y3, pooled);
    k_ch<<<dim3(1), dim3(64), 0, stream>>>(pooled, ch_w1, ch_b1, ch_w2, ch_b2, chbuf);
    k_ddf<<<grd, blk, 0, stream>>>(y3, sp_w, sp_b, chbuf, out);
}